// Round 1
// baseline (777.874 us; speedup 1.0000x reference)
//
#include <hip/hip_runtime.h>
#include <math.h>

#define BB 1024
#define NI 50000
#define NI4 (NI / 4)   // 12500 float4 per row
#define DD 256

// ws layout (floats): [0..2] = sum_b (dot_k - lse_k*sx) for k=merged,text,rec
//                     [3] = kld1 elementwise sum, [4] = kld2 sum, [5] = wass sum

__global__ void zero_ws_kernel(float* ws) {
    if (threadIdx.x < 6) ws[threadIdx.x] = 0.0f;
}

__device__ inline float wave_red(float v) {
    #pragma unroll
    for (int o = 32; o > 0; o >>= 1) v += __shfl_down(v, o, 64);
    return v;
}

// One block per row. Streams recon_x, logits_text, logits_rec, x once.
__global__ __launch_bounds__(256) void bce_rows_kernel(
        const float* __restrict__ recon, const float* __restrict__ x,
        const float* __restrict__ ltxt,  const float* __restrict__ lrec,
        float* __restrict__ ws) {
    const long base = (long)blockIdx.x * NI;
    const float4* __restrict__ x4 = (const float4*)(x     + base);
    const float4* __restrict__ a4 = (const float4*)(recon + base);
    const float4* __restrict__ b4 = (const float4*)(ltxt  + base);
    const float4* __restrict__ c4 = (const float4*)(lrec  + base);

    float s0 = 0.f, d0 = 0.f, s1 = 0.f, d1 = 0.f, s2 = 0.f, d2 = 0.f, sx = 0.f;

    for (int i = threadIdx.x; i < NI4; i += 256) {
        float4 xv = x4[i];
        float4 av = a4[i];
        float4 bv = b4[i];
        float4 cv = c4[i];

        s0 += __expf(av.x) + __expf(av.y) + __expf(av.z) + __expf(av.w);
        d0  = fmaf(av.x, xv.x, fmaf(av.y, xv.y, fmaf(av.z, xv.z, fmaf(av.w, xv.w, d0))));

        s1 += __expf(bv.x) + __expf(bv.y) + __expf(bv.z) + __expf(bv.w);
        d1  = fmaf(bv.x, xv.x, fmaf(bv.y, xv.y, fmaf(bv.z, xv.z, fmaf(bv.w, xv.w, d1))));

        s2 += __expf(cv.x) + __expf(cv.y) + __expf(cv.z) + __expf(cv.w);
        d2  = fmaf(cv.x, xv.x, fmaf(cv.y, xv.y, fmaf(cv.z, xv.z, fmaf(cv.w, xv.w, d2))));

        sx += xv.x + xv.y + xv.z + xv.w;
    }

    float vals[7] = {s0, d0, s1, d1, s2, d2, sx};
    #pragma unroll
    for (int j = 0; j < 7; ++j) vals[j] = wave_red(vals[j]);

    __shared__ float red[4][7];
    const int lane = threadIdx.x & 63, wave = threadIdx.x >> 6;
    if (lane == 0) {
        #pragma unroll
        for (int j = 0; j < 7; ++j) red[wave][j] = vals[j];
    }
    __syncthreads();

    if (threadIdx.x == 0) {
        float t[7];
        #pragma unroll
        for (int j = 0; j < 7; ++j)
            t[j] = red[0][j] + red[1][j] + red[2][j] + red[3][j];
        const float sxr = t[6];
        atomicAdd(&ws[0], t[1] - logf(t[0]) * sxr);
        atomicAdd(&ws[1], t[3] - logf(t[2]) * sxr);
        atomicAdd(&ws[2], t[5] - logf(t[4]) * sxr);
    }
}

// Elementwise-separable small terms over B*D.
__global__ __launch_bounds__(256) void small_terms_kernel(
        const float* __restrict__ z,   const float* __restrict__ mu,
        const float* __restrict__ lv,  const float* __restrict__ pmu,
        const float* __restrict__ plv, float* __restrict__ ws) {
    float k1 = 0.f, k2 = 0.f, w = 0.f;
    const int stride = gridDim.x * 256;
    for (int i = blockIdx.x * 256 + threadIdx.x; i < BB * DD; i += stride) {
        float m  = mu[i],  l  = lv[i], zz = z[i];
        float pm = pmu[i], pl = plv[i];
        float el  = __expf(l);
        float epl = __expf(pl);
        k1 += 1.f + l - m * m - el;                       // KLD1 term
        float dz = zz - pm;
        k2 += -0.5f * (pl + dz * dz * __expf(-pl) - zz * zz);  // KLD2 term
        float dm = m - pm;
        w += dm * dm + el + epl - 2.f * __expf(0.5f * (l + pl));  // BW term
    }

    k1 = wave_red(k1); k2 = wave_red(k2); w = wave_red(w);

    __shared__ float red[4][3];
    const int lane = threadIdx.x & 63, wave = threadIdx.x >> 6;
    if (lane == 0) { red[wave][0] = k1; red[wave][1] = k2; red[wave][2] = w; }
    __syncthreads();
    if (threadIdx.x == 0) {
        atomicAdd(&ws[3], red[0][0] + red[1][0] + red[2][0] + red[3][0]);
        atomicAdd(&ws[4], red[0][1] + red[1][1] + red[2][1] + red[3][1]);
        atomicAdd(&ws[5], red[0][2] + red[1][2] + red[2][2] + red[3][2]);
    }
}

__global__ void finalize_kernel(const float* __restrict__ ws, float* __restrict__ out) {
    if (threadIdx.x == 0 && blockIdx.x == 0) {
        const float invBN = 1.0f / ((float)BB * (float)NI);
        const float bce_m = -ws[0] * invBN;
        const float bce_t = -ws[1] * invBN;
        const float bce_r = -ws[2] * invBN;
        const float BCE   = (bce_m + bce_t + bce_r) / 3.0f;
        const float kld1  = -0.5f * ws[3] / ((float)BB * (float)DD);
        const float kld2  =         ws[4] / ((float)BB * (float)DD);
        const float wass  =         ws[5] / (float)BB;
        out[0] = BCE + 0.5f * (kld1 + kld2) + wass;  // ANNEAL=1, EPSILON=1
        out[1] = BCE;
        out[2] = wass;
        out[3] = bce_r;
        out[4] = bce_t;
        out[5] = bce_m;
    }
}

extern "C" void kernel_launch(void* const* d_in, const int* in_sizes, int n_in,
                              void* d_out, int out_size, void* d_ws, size_t ws_size,
                              hipStream_t stream) {
    const float* recon = (const float*)d_in[0];
    const float* x     = (const float*)d_in[1];
    const float* z     = (const float*)d_in[2];
    const float* mu    = (const float*)d_in[3];
    const float* lv    = (const float*)d_in[4];
    const float* ltxt  = (const float*)d_in[5];
    const float* lrec  = (const float*)d_in[6];
    const float* pmu   = (const float*)d_in[7];
    const float* plv   = (const float*)d_in[8];
    // d_in[9] (train_items) is unused by the reference.

    float* ws  = (float*)d_ws;
    float* out = (float*)d_out;

    zero_ws_kernel<<<1, 64, 0, stream>>>(ws);
    bce_rows_kernel<<<BB, 256, 0, stream>>>(recon, x, ltxt, lrec, ws);
    small_terms_kernel<<<256, 256, 0, stream>>>(z, mu, lv, pmu, plv, ws);
    finalize_kernel<<<1, 64, 0, stream>>>(ws, out);
}

// Round 2
// 757.178 us; speedup vs baseline: 1.0273x; 1.0273x over previous
//
#include <hip/hip_runtime.h>
#include <math.h>

#define BB 1024
#define NI 50000
#define NI4 (NI / 4)   // 12500 float4 per row
#define DD 256
#define BT 1024        // threads per block in bce_rows (16 waves -> full occupancy)

// ws layout (floats): [0..2] = sum_b (dot_k - log(sumexp_k)*sx_b) for k=merged,text,rec
//                     [3] = kld1 elementwise sum, [4] = kld2 sum, [5] = wass sum

__global__ void zero_ws_kernel(float* ws) {
    if (threadIdx.x < 6) ws[threadIdx.x] = 0.0f;
}

__device__ inline float wave_red(float v) {
    #pragma unroll
    for (int o = 32; o > 0; o >>= 1) v += __shfl_down(v, o, 64);
    return v;
}

// One block per row, 1024 threads. Streams recon_x, logits_text, logits_rec, x once.
__global__ __launch_bounds__(BT) void bce_rows_kernel(
        const float* __restrict__ recon, const float* __restrict__ x,
        const float* __restrict__ ltxt,  const float* __restrict__ lrec,
        float* __restrict__ ws) {
    const long base = (long)blockIdx.x * NI;
    const float4* __restrict__ x4 = (const float4*)(x     + base);
    const float4* __restrict__ a4 = (const float4*)(recon + base);
    const float4* __restrict__ b4 = (const float4*)(ltxt  + base);
    const float4* __restrict__ c4 = (const float4*)(lrec  + base);

    float s0 = 0.f, d0 = 0.f, s1 = 0.f, d1 = 0.f, s2 = 0.f, d2 = 0.f, sx = 0.f;

    // Unroll x2: 8 dwordx4 loads in flight per wave before the first waitcnt-use.
    int i = threadIdx.x;
    for (; i + BT < NI4; i += 2 * BT) {
        float4 xv0 = x4[i];       float4 xv1 = x4[i + BT];
        float4 av0 = a4[i];       float4 av1 = a4[i + BT];
        float4 bv0 = b4[i];       float4 bv1 = b4[i + BT];
        float4 cv0 = c4[i];       float4 cv1 = c4[i + BT];

        s0 += __expf(av0.x) + __expf(av0.y) + __expf(av0.z) + __expf(av0.w)
            + __expf(av1.x) + __expf(av1.y) + __expf(av1.z) + __expf(av1.w);
        d0  = fmaf(av0.x, xv0.x, fmaf(av0.y, xv0.y, fmaf(av0.z, xv0.z, fmaf(av0.w, xv0.w, d0))));
        d0  = fmaf(av1.x, xv1.x, fmaf(av1.y, xv1.y, fmaf(av1.z, xv1.z, fmaf(av1.w, xv1.w, d0))));

        s1 += __expf(bv0.x) + __expf(bv0.y) + __expf(bv0.z) + __expf(bv0.w)
            + __expf(bv1.x) + __expf(bv1.y) + __expf(bv1.z) + __expf(bv1.w);
        d1  = fmaf(bv0.x, xv0.x, fmaf(bv0.y, xv0.y, fmaf(bv0.z, xv0.z, fmaf(bv0.w, xv0.w, d1))));
        d1  = fmaf(bv1.x, xv1.x, fmaf(bv1.y, xv1.y, fmaf(bv1.z, xv1.z, fmaf(bv1.w, xv1.w, d1))));

        s2 += __expf(cv0.x) + __expf(cv0.y) + __expf(cv0.z) + __expf(cv0.w)
            + __expf(cv1.x) + __expf(cv1.y) + __expf(cv1.z) + __expf(cv1.w);
        d2  = fmaf(cv0.x, xv0.x, fmaf(cv0.y, xv0.y, fmaf(cv0.z, xv0.z, fmaf(cv0.w, xv0.w, d2))));
        d2  = fmaf(cv1.x, xv1.x, fmaf(cv1.y, xv1.y, fmaf(cv1.z, xv1.z, fmaf(cv1.w, xv1.w, d2))));

        sx += xv0.x + xv0.y + xv0.z + xv0.w
            + xv1.x + xv1.y + xv1.z + xv1.w;
    }
    for (; i < NI4; i += BT) {
        float4 xv = x4[i];
        float4 av = a4[i];
        float4 bv = b4[i];
        float4 cv = c4[i];
        s0 += __expf(av.x) + __expf(av.y) + __expf(av.z) + __expf(av.w);
        d0  = fmaf(av.x, xv.x, fmaf(av.y, xv.y, fmaf(av.z, xv.z, fmaf(av.w, xv.w, d0))));
        s1 += __expf(bv.x) + __expf(bv.y) + __expf(bv.z) + __expf(bv.w);
        d1  = fmaf(bv.x, xv.x, fmaf(bv.y, xv.y, fmaf(bv.z, xv.z, fmaf(bv.w, xv.w, d1))));
        s2 += __expf(cv.x) + __expf(cv.y) + __expf(cv.z) + __expf(cv.w);
        d2  = fmaf(cv.x, xv.x, fmaf(cv.y, xv.y, fmaf(cv.z, xv.z, fmaf(cv.w, xv.w, d2))));
        sx += xv.x + xv.y + xv.z + xv.w;
    }

    float vals[7] = {s0, d0, s1, d1, s2, d2, sx};
    #pragma unroll
    for (int j = 0; j < 7; ++j) vals[j] = wave_red(vals[j]);

    __shared__ float red[BT / 64][7];
    const int lane = threadIdx.x & 63, wave = threadIdx.x >> 6;
    if (lane == 0) {
        #pragma unroll
        for (int j = 0; j < 7; ++j) red[wave][j] = vals[j];
    }
    __syncthreads();

    if (threadIdx.x == 0) {
        float t[7];
        #pragma unroll
        for (int j = 0; j < 7; ++j) {
            float acc = 0.f;
            #pragma unroll
            for (int w = 0; w < BT / 64; ++w) acc += red[w][j];
            t[j] = acc;
        }
        const float sxr = t[6];
        atomicAdd(&ws[0], t[1] - logf(t[0]) * sxr);
        atomicAdd(&ws[1], t[3] - logf(t[2]) * sxr);
        atomicAdd(&ws[2], t[5] - logf(t[4]) * sxr);
    }
}

// Elementwise-separable small terms over B*D.
__global__ __launch_bounds__(256) void small_terms_kernel(
        const float* __restrict__ z,   const float* __restrict__ mu,
        const float* __restrict__ lv,  const float* __restrict__ pmu,
        const float* __restrict__ plv, float* __restrict__ ws) {
    float k1 = 0.f, k2 = 0.f, w = 0.f;
    const int stride = gridDim.x * 256;
    for (int i = blockIdx.x * 256 + threadIdx.x; i < BB * DD; i += stride) {
        float m  = mu[i],  l  = lv[i], zz = z[i];
        float pm = pmu[i], pl = plv[i];
        float el  = __expf(l);
        float epl = __expf(pl);
        k1 += 1.f + l - m * m - el;                       // KLD1 term
        float dz = zz - pm;
        k2 += -0.5f * (pl + dz * dz * __expf(-pl) - zz * zz);  // KLD2 term
        float dm = m - pm;
        w += dm * dm + el + epl - 2.f * __expf(0.5f * (l + pl));  // BW term
    }

    k1 = wave_red(k1); k2 = wave_red(k2); w = wave_red(w);

    __shared__ float red[4][3];
    const int lane = threadIdx.x & 63, wave = threadIdx.x >> 6;
    if (lane == 0) { red[wave][0] = k1; red[wave][1] = k2; red[wave][2] = w; }
    __syncthreads();
    if (threadIdx.x == 0) {
        atomicAdd(&ws[3], red[0][0] + red[1][0] + red[2][0] + red[3][0]);
        atomicAdd(&ws[4], red[0][1] + red[1][1] + red[2][1] + red[3][1]);
        atomicAdd(&ws[5], red[0][2] + red[1][2] + red[2][2] + red[3][2]);
    }
}

__global__ void finalize_kernel(const float* __restrict__ ws, float* __restrict__ out) {
    if (threadIdx.x == 0 && blockIdx.x == 0) {
        const float invBN = 1.0f / ((float)BB * (float)NI);
        const float bce_m = -ws[0] * invBN;
        const float bce_t = -ws[1] * invBN;
        const float bce_r = -ws[2] * invBN;
        const float BCE   = (bce_m + bce_t + bce_r) / 3.0f;
        const float kld1  = -0.5f * ws[3] / ((float)BB * (float)DD);
        const float kld2  =         ws[4] / ((float)BB * (float)DD);
        const float wass  =         ws[5] / (float)BB;
        out[0] = BCE + 0.5f * (kld1 + kld2) + wass;  // ANNEAL=1, EPSILON=1
        out[1] = BCE;
        out[2] = wass;
        out[3] = bce_r;
        out[4] = bce_t;
        out[5] = bce_m;
    }
}

extern "C" void kernel_launch(void* const* d_in, const int* in_sizes, int n_in,
                              void* d_out, int out_size, void* d_ws, size_t ws_size,
                              hipStream_t stream) {
    const float* recon = (const float*)d_in[0];
    const float* x     = (const float*)d_in[1];
    const float* z     = (const float*)d_in[2];
    const float* mu    = (const float*)d_in[3];
    const float* lv    = (const float*)d_in[4];
    const float* ltxt  = (const float*)d_in[5];
    const float* lrec  = (const float*)d_in[6];
    const float* pmu   = (const float*)d_in[7];
    const float* plv   = (const float*)d_in[8];
    // d_in[9] (train_items) is unused by the reference.

    float* ws  = (float*)d_ws;
    float* out = (float*)d_out;

    zero_ws_kernel<<<1, 64, 0, stream>>>(ws);
    bce_rows_kernel<<<BB, BT, 0, stream>>>(recon, x, ltxt, lrec, ws);
    small_terms_kernel<<<256, 256, 0, stream>>>(z, mu, lv, pmu, plv, ws);
    finalize_kernel<<<1, 64, 0, stream>>>(ws, out);
}